// Round 5
// baseline (2221.261 us; speedup 1.0000x reference)
//
#include <hip/hip_runtime.h>
#include <hip/hip_fp16.h>

#define N_NODES 100000
#define N_EDGES 1600000
#define HID 64

#define BSH 8                         // bucket = dst >> 8 (256 nodes per bucket)
#define NBKT ((N_NODES + 255) / 256)  // 391
#define CAP 6144                      // fixed tmp region per bucket (mean 4093, sd 64)
#define TILE 4096                     // edges per bucket_kernel block (32 KB LDS)

#define HSC 0.015625f                 // 1/64: fp16 range scaling for h/aout (exact pow2)
#define HSCI 64.0f

typedef _Float16 f16x8 __attribute__((ext_vector_type(8)));
typedef float f32x4 __attribute__((ext_vector_type(4)));

// Pass A: bin edges by dst-bucket into fixed-capacity bucket regions of tmp.
// bcur is a zero-initialized per-bucket counter (region base = b*CAP).
// packed tmp word: (dst & 255) << 17 | src   (src < 2^17)
// tmp PERSISTS across all 3 layers (edge list for agg_kernel) — dedicated
// workspace region (ws is ~268 MB per the poison fills; no aliasing).
__global__ void __launch_bounds__(512) bucket_kernel(const int* __restrict__ src,
                                                     const int* __restrict__ dst,
                                                     int* __restrict__ bcur,
                                                     unsigned int* __restrict__ tmp) {
    __shared__ unsigned long long ed[TILE];  // 32 KB staged (dst<<32 | src)
    __shared__ int cnt[NBKT], cnt2[NBKT], scnx[NBKT], gbase[NBKT];
    __shared__ int s[512];
    int tid = threadIdx.x;
    int bstart = blockIdx.x * TILE;
    int tcnt = N_EDGES - bstart;
    if (tcnt > TILE) tcnt = TILE;
    if (tcnt < 0) tcnt = 0;
    for (int b = tid; b < NBKT; b += 512) { cnt[b] = 0; cnt2[b] = 0; }
    __syncthreads();
    for (int i = tid; i < tcnt; i += 512) atomicAdd(&cnt[dst[bstart + i] >> BSH], 1);
    __syncthreads();
    s[tid] = (tid < NBKT) ? cnt[tid] : 0;
    __syncthreads();
    for (int off = 1; off < 512; off <<= 1) {
        int add = (tid >= off) ? s[tid - off] : 0;
        __syncthreads();
        s[tid] += add;
        __syncthreads();
    }
    if (tid < NBKT) {
        scnx[tid] = s[tid] - cnt[tid];
        gbase[tid] = tid * CAP + atomicAdd(&bcur[tid], cnt[tid]);
    }
    __syncthreads();
    for (int i = tid; i < tcnt; i += 512) {
        int e = bstart + i;
        int d = dst[e], sc = src[e];
        int b = d >> BSH;
        int pos = scnx[b] + atomicAdd(&cnt2[b], 1);
        ed[pos] = ((unsigned long long)(unsigned)d << 32) | (unsigned)sc;
    }
    __syncthreads();
    for (int i = tid; i < tcnt; i += 512) {
        unsigned long long v = ed[i];
        int d = (int)(v >> 32);
        unsigned sc = (unsigned)v;
        int b = d >> BSH;
        int idx = gbase[b] + (i - scnx[b]);
        if (idx < (b + 1) * CAP)  // statistically unreachable guard
            tmp[idx] = ((unsigned)(d & 255) << 17) | sc;
    }
}

// MFMA f16 dual GEMM: m = fp16(h_scaled @ relW.T), aout = fp16-scaled root term.
// Scaling identities (all exact pow2): A = HSC*h (PRE=0) or h (PRE=1);
//   m   = A @ relW.T                      (== mscale*(h@relW.T) since HSCI*mscale==1)
//   aout= A @ rootW.T * (PRE?HSC:1) + relb*HSC   (== HSC*(h@rootW.T + relb))
// Block tile 128 nodes x 128 outs (64 rel | 64 root), 4 waves 2x2, each wave
// 64x64 via 4x4 fragments x 2 K-steps of v_mfma_f32_16x16x32_f16.
// LDS fp16 with 16B-chunk XOR swizzle (chunk ^= row&7) -> conflict-free
// ds_read_b128 at 128B row stride (G4 recipe). All loads default-cached
// (R3 post-mortem: nontemporal hints regressed +16 µs — do not reintroduce).
template <int PRE>
__global__ void __launch_bounds__(256) gemmt_kernel(const void* __restrict__ hx,
                                                    const float* __restrict__ preW,
                                                    const float* __restrict__ preb,
                                                    const float* __restrict__ relW,
                                                    const float* __restrict__ relb,
                                                    const float* __restrict__ rootW,
                                                    __half* __restrict__ m,
                                                    __half* __restrict__ aout) {
    __shared__ __align__(16) __half hs[128 * 64];
    __shared__ __align__(16) __half ws[128 * 64];
    __shared__ float xs[PRE ? 384 : 1];
    __shared__ float pw[PRE ? 192 : 1];
    __shared__ float pbs[PRE ? 64 : 1];
    int tid = threadIdx.x;
    int i0 = blockIdx.x * 128;

    // stage weights fp32 -> fp16, swizzled. 1024 16B chunks (row 0..127, c 0..7)
#pragma unroll
    for (int it = 0; it < 4; it++) {
        int t = it * 256 + tid;
        int row = t >> 3, c = t & 7;
        const float* wsrc = (row < 64) ? &relW[row * 64 + c * 8]
                                       : &rootW[(row - 64) * 64 + c * 8];
        float4 w0 = *(const float4*)wsrc;
        float4 w1 = *(const float4*)(wsrc + 4);
        uint4 pk;
        __half2* hp = (__half2*)&pk;
        hp[0] = __floats2half2_rn(w0.x, w0.y);
        hp[1] = __floats2half2_rn(w0.z, w0.w);
        hp[2] = __floats2half2_rn(w1.x, w1.y);
        hp[3] = __floats2half2_rn(w1.z, w1.w);
        *(uint4*)&ws[row * 64 + ((c ^ (row & 7)) << 3)] = pk;
    }
    if (PRE) {
        const float* x = (const float*)hx;
        if (tid < 192) pw[tid] = preW[tid];
        if (tid < 64) pbs[tid] = preb[tid];
        for (int t = tid; t < 384; t += 256) {  // FULL coverage of xs[0..383]
            int gi = i0 * 3 + t;
            xs[t] = (gi < N_NODES * 3) ? x[gi] : 0.f;
        }
        __syncthreads();
#pragma unroll
        for (int it = 0; it < 4; it++) {
            int t = it * 256 + tid;
            int row = t >> 3, c = t & 7;
            float v[8];
#pragma unroll
            for (int u = 0; u < 8; u++) {
                int col = c * 8 + u;
                float sv = pbs[col];
                sv = fmaf(xs[row * 3 + 0], pw[col * 3 + 0], sv);
                sv = fmaf(xs[row * 3 + 1], pw[col * 3 + 1], sv);
                sv = fmaf(xs[row * 3 + 2], pw[col * 3 + 2], sv);
                v[u] = fmaxf(sv, 0.f);
            }
            uint4 pk;
            __half2* hp = (__half2*)&pk;
            hp[0] = __floats2half2_rn(v[0], v[1]);
            hp[1] = __floats2half2_rn(v[2], v[3]);
            hp[2] = __floats2half2_rn(v[4], v[5]);
            hp[3] = __floats2half2_rn(v[6], v[7]);
            *(uint4*)&hs[row * 64 + ((c ^ (row & 7)) << 3)] = pk;
        }
    } else {
        const __half* h = (const __half*)hx;
#pragma unroll
        for (int it = 0; it < 4; it++) {
            int t = it * 256 + tid;
            int row = t >> 3, c = t & 7;
            uint4 hv = {0u, 0u, 0u, 0u};
            if (i0 + row < N_NODES) hv = *(const uint4*)(h + (long)(i0 + row) * 64 + c * 8);
            *(uint4*)&hs[row * 64 + ((c ^ (row & 7)) << 3)] = hv;
        }
    }
    __syncthreads();

    int lane = tid & 63;
    int w = tid >> 6;          // wave 0..3
    int wm = w >> 1, wn = w & 1;  // 2x2 wave grid: wm = node half, wn = out half
    int r = lane & 15, q = lane >> 4;

    f32x4 acc[4][4];
#pragma unroll
    for (int mt = 0; mt < 4; mt++)
#pragma unroll
        for (int nt = 0; nt < 4; nt++) acc[mt][nt] = (f32x4){0.f, 0.f, 0.f, 0.f};

#pragma unroll
    for (int ks = 0; ks < 2; ks++) {
        f16x8 af[4], bf[4];
#pragma unroll
        for (int mt = 0; mt < 4; mt++) {
            int row = wm * 64 + mt * 16 + r;
            int cc = (ks * 4 + q) ^ (row & 7);
            af[mt] = *(const f16x8*)&hs[row * 64 + (cc << 3)];
        }
#pragma unroll
        for (int nt = 0; nt < 4; nt++) {
            int row = wn * 64 + nt * 16 + r;
            int cc = (ks * 4 + q) ^ (row & 7);
            bf[nt] = *(const f16x8*)&ws[row * 64 + (cc << 3)];
        }
#pragma unroll
        for (int mt = 0; mt < 4; mt++)
#pragma unroll
            for (int nt = 0; nt < 4; nt++)
                acc[mt][nt] = __builtin_amdgcn_mfma_f32_16x16x32_f16(af[mt], bf[nt],
                                                                     acc[mt][nt], 0, 0, 0);
    }

    // epilogue: wn==0 waves own rel cols 0..63 -> m; wn==1 own root cols -> aout
    if (wn == 0) {
#pragma unroll
        for (int mt = 0; mt < 4; mt++) {
            int nb = i0 + wm * 64 + mt * 16 + q * 4;
#pragma unroll
            for (int reg = 0; reg < 4; reg++) {
                int node = nb + reg;
                if (node >= N_NODES) continue;
#pragma unroll
                for (int nt = 0; nt < 4; nt++)
                    m[(long)node * 64 + nt * 16 + r] = __float2half(acc[mt][nt][reg]);
            }
        }
    } else {
        const float asc = PRE ? HSC : 1.0f;
        float rb[4];
#pragma unroll
        for (int nt = 0; nt < 4; nt++) rb[nt] = relb[nt * 16 + r] * HSC;
#pragma unroll
        for (int mt = 0; mt < 4; mt++) {
            int nb = i0 + wm * 64 + mt * 16 + q * 4;
#pragma unroll
            for (int reg = 0; reg < 4; reg++) {
                int node = nb + reg;
                if (node >= N_NODES) continue;
#pragma unroll
                for (int nt = 0; nt < 4; nt++)
                    aout[(long)node * 64 + nt * 16 + r] =
                        __float2half(fmaf(acc[mt][nt][reg], asc, rb[nt]));
            }
        }
    }
}

// Edge-parallel bucket aggregation (replaces passb + gather). Block = bucket b
// (256 dst nodes). fp32 accumulator tile [256][65] in LDS (pad +1 float keeps
// finalize reads conflict-free). Edges streamed from tmp in 2048-word chunks;
// 8-lane groups read one m-row (coalesced 128 B) and do 8 LDS atomicAdds each,
// 4 edges in flight per lane (MLP). FP sum order was already nondeterministic
// in the CSR path (atomic scatter), so LDS-atomic order is the same contract.
// Finalize: thread t owns node b*256+t: h = relu(acc*aggscale + aout*HSCI);
// FINAL: out = relu(h @ postW.T + postb); else store fp16 HSC*h in place of a.
// NOTE (R4 bug): macro params must not be named like vector members — a param
// named `w` was substituted into `(u).w` by the preprocessor.
template <int FINAL>
__global__ void __launch_bounds__(512) agg_kernel(const unsigned int* __restrict__ tmp,
                                                  const int* __restrict__ bcur,
                                                  const __half* __restrict__ m,
                                                  __half* __restrict__ a,
                                                  float aggscale,
                                                  const float* __restrict__ postW,
                                                  const float* __restrict__ postb,
                                                  float* __restrict__ out) {
    __shared__ float acc[256 * 65];     // 66.56 KB
    __shared__ unsigned ebuf[2048];     // 8 KB edge stage
    __shared__ float pws[128];          // postW stage (FINAL only; 512 B)
    __shared__ float pbss[2];
    int tid = threadIdx.x;
    int b = blockIdx.x;
    int ne = bcur[b];
    if (ne > CAP) ne = CAP;
    for (int i = tid; i < 256 * 65; i += 512) acc[i] = 0.f;
    if (FINAL) {
        if (tid < 128) pws[tid] = postW[tid];
        if (tid < 2) pbss[tid] = postb[tid];
    }
    __syncthreads();
    const unsigned* tb = tmp + (size_t)b * CAP;
    int sl = tid >> 3;           // edge slot 0..63
    int f8 = (tid & 7) << 3;     // feature oct base
#define ADD8(ew, uv)                                                        \
    {                                                                       \
        float* ap = &acc[(int)((ew) >> 17) * 65 + f8];                      \
        float2 f_;                                                          \
        f_ = __half22float2(*(__half2*)&(uv).x);                            \
        atomicAdd(ap + 0, f_.x); atomicAdd(ap + 1, f_.y);                   \
        f_ = __half22float2(*(__half2*)&(uv).y);                            \
        atomicAdd(ap + 2, f_.x); atomicAdd(ap + 3, f_.y);                   \
        f_ = __half22float2(*(__half2*)&(uv).z);                            \
        atomicAdd(ap + 4, f_.x); atomicAdd(ap + 5, f_.y);                   \
        f_ = __half22float2(*(__half2*)&(uv).w);                            \
        atomicAdd(ap + 6, f_.x); atomicAdd(ap + 7, f_.y);                   \
    }
    for (int ch = 0; ch < CAP; ch += 2048) {
        if (ch >= ne) break;
        *(uint4*)&ebuf[tid * 4] = *(const uint4*)&tb[ch + tid * 4];
        __syncthreads();
        int lim = ne - ch;
        if (lim > 2048) lim = 2048;
        for (int ps = 0; ps < 2048; ps += 256) {
            if (ps >= lim) break;
            int e0 = ps + sl, e1 = e0 + 64, e2 = e0 + 128, e3 = e0 + 192;
            bool v0 = e0 < lim, v1 = e1 < lim, v2 = e2 < lim, v3 = e3 < lim;
            unsigned w0 = ebuf[e0 & 2047], w1 = ebuf[e1 & 2047];
            unsigned w2 = ebuf[e2 & 2047], w3 = ebuf[e3 & 2047];
            uint4 u0 = {0, 0, 0, 0}, u1 = {0, 0, 0, 0};
            uint4 u2 = {0, 0, 0, 0}, u3 = {0, 0, 0, 0};
            if (v0) u0 = *(const uint4*)(m + (long)(w0 & 0x1FFFF) * 64 + f8);
            if (v1) u1 = *(const uint4*)(m + (long)(w1 & 0x1FFFF) * 64 + f8);
            if (v2) u2 = *(const uint4*)(m + (long)(w2 & 0x1FFFF) * 64 + f8);
            if (v3) u3 = *(const uint4*)(m + (long)(w3 & 0x1FFFF) * 64 + f8);
            if (v0) ADD8(w0, u0);
            if (v1) ADD8(w1, u1);
            if (v2) ADD8(w2, u2);
            if (v3) ADD8(w3, u3);
        }
        __syncthreads();
    }
#undef ADD8
    __syncthreads();
    if (tid < 256) {
        int node = (b << 8) + tid;
        if (node < N_NODES) {
            const __half* arow = a + (long)node * 64;
            float res[64];
#pragma unroll
            for (int c = 0; c < 8; c++) {
                uint4 av = *(const uint4*)(arow + c * 8);
                const __half2* ap2 = (const __half2*)&av;
#pragma unroll
                for (int k = 0; k < 4; k++) {
                    float2 fo = __half22float2(ap2[k]);
                    float s0 = acc[tid * 65 + c * 8 + 2 * k] * aggscale;
                    float s1 = acc[tid * 65 + c * 8 + 2 * k + 1] * aggscale;
                    res[c * 8 + 2 * k] = fmaxf(fmaf(fo.x, HSCI, s0), 0.f);
                    res[c * 8 + 2 * k + 1] = fmaxf(fmaf(fo.y, HSCI, s1), 0.f);
                }
            }
            if (FINAL) {
                float p0 = pbss[0], p1 = pbss[1];
#pragma unroll
                for (int f = 0; f < 64; f++) {
                    p0 = fmaf(res[f], pws[f], p0);
                    p1 = fmaf(res[f], pws[64 + f], p1);
                }
                out[(long)node * 2 + 0] = fmaxf(p0, 0.f);
                out[(long)node * 2 + 1] = fmaxf(p1, 0.f);
            } else {
                __half* hw = a + (long)node * 64;
#pragma unroll
                for (int c = 0; c < 8; c++) {
                    uint4 st;
                    __half2* sp = (__half2*)&st;
                    sp[0] = __floats2half2_rn(res[c * 8 + 0] * HSC, res[c * 8 + 1] * HSC);
                    sp[1] = __floats2half2_rn(res[c * 8 + 2] * HSC, res[c * 8 + 3] * HSC);
                    sp[2] = __floats2half2_rn(res[c * 8 + 4] * HSC, res[c * 8 + 5] * HSC);
                    sp[3] = __floats2half2_rn(res[c * 8 + 6] * HSC, res[c * 8 + 7] * HSC);
                    *(uint4*)(hw + c * 8) = st;
                }
            }
        }
    }
}

extern "C" void kernel_launch(void* const* d_in, const int* in_sizes, int n_in,
                              void* d_out, int out_size, void* d_ws, size_t ws_size,
                              hipStream_t stream) {
    const float* x = (const float*)d_in[0];
    const int* esrc = (const int*)d_in[1];
    const int* edst = esrc + N_EDGES;
    const float* preW = (const float*)d_in[2];
    const float* preb = (const float*)d_in[3];
    const float* postW = (const float*)d_in[4];
    const float* postb = (const float*)d_in[5];
    const float* relW[3] = {(const float*)d_in[6], (const float*)d_in[9], (const float*)d_in[12]};
    const float* relb[3] = {(const float*)d_in[7], (const float*)d_in[10], (const float*)d_in[13]};
    const float* rootW[3] = {(const float*)d_in[8], (const float*)d_in[11], (const float*)d_in[14]};
    float* out = (float*)d_out;

    const size_t NF = (size_t)N_NODES * HID;
    char* p = (char*)d_ws;
    __half* hA = (__half*)p; p += NF * 2;
    __half* hB = (__half*)p; p += NF * 2;
    __half* mB = (__half*)p; p += NF * 2;
    p = (char*)(((size_t)p + 255) & ~(size_t)255);
    unsigned int* tmp = (unsigned int*)p; p += (size_t)NBKT * CAP * 4;  // 9.6 MB, persists
    int* bcur = (int*)p; p += 512 * 4;

    // --- build bucketed edge list (by dst): fixed-cap bins, persists 3 layers ---
    hipMemsetAsync(bcur, 0, 512 * 4, stream);
    bucket_kernel<<<(N_EDGES + TILE - 1) / TILE, 512, 0, stream>>>(esrc, edst, bcur, tmp);

    const int GEMM_BLOCKS = (N_NODES + 127) / 128;      // 782

    const float IS1 = 64.0f;  // layers 1-2 m fp16 range scaling inverse

    // layer 0 (pre fused): x -> mB, hB(aout); m = h@relW.T exact (msc==1)
    gemmt_kernel<1><<<GEMM_BLOCKS, 256, 0, stream>>>(x, preW, preb, relW[0], relb[0],
                                                     rootW[0], mB, hB);
    agg_kernel<0><<<NBKT, 512, 0, stream>>>(tmp, bcur, mB, hB, 1.0f,
                                            nullptr, nullptr, nullptr);
    // layer 1: hB -> mB, hA(aout); m = HSC*(h@relW.T) via A=HSC*h (msc==1)
    gemmt_kernel<0><<<GEMM_BLOCKS, 256, 0, stream>>>(hB, nullptr, nullptr, relW[1], relb[1],
                                                     rootW[1], mB, hA);
    agg_kernel<0><<<NBKT, 512, 0, stream>>>(tmp, bcur, mB, hA, IS1,
                                            nullptr, nullptr, nullptr);
    // layer 2 + post: hA -> out
    gemmt_kernel<0><<<GEMM_BLOCKS, 256, 0, stream>>>(hA, nullptr, nullptr, relW[2], relb[2],
                                                     rootW[2], mB, hB);
    agg_kernel<1><<<NBKT, 512, 0, stream>>>(tmp, bcur, mB, hB, IS1,
                                            postW, postb, out);
}

// Round 6
// 252.171 us; speedup vs baseline: 8.8085x; 8.8085x over previous
//
#include <hip/hip_runtime.h>
#include <hip/hip_fp16.h>

#define N_NODES 100000
#define N_EDGES 1600000
#define HID 64

#define BSH 8                         // bucket = dst >> 8 (256 nodes per bucket)
#define NBKT ((N_NODES + 255) / 256)  // 391
#define CAP 6144                      // fixed tmp region per bucket (mean 4093, sd 64)
#define TILE 4096                     // edges per bucket chunk (32 KB LDS)
#define NCHUNK ((N_EDGES + TILE - 1) / TILE)  // 391

#define HSC 0.015625f                 // 1/64: fp16 range scaling for h/aout (exact pow2)
#define HSCI 64.0f

typedef _Float16 f16x8 __attribute__((ext_vector_type(8)));
typedef float f32x4 __attribute__((ext_vector_type(4)));

// Fused {edge bucketing ∥ layer-0 PRE-gemm} fat kernel.
// Blocks [0, NCHUNK): bin a 4096-edge chunk by dst-bucket into tmp (verbatim
//   R1 bucket_kernel body, pointers into dynamic LDS).
// Blocks [NCHUNK, NCHUNK+782): one 128-node tile of the PRE gemm at 512 thr
//   (8 waves, wave grid 4x2, acc[2][4]) — independent of the CSR build, so the
//   GPU overlaps it with bucketing instead of serializing two launches.
// Dynamic LDS union: bucket 41216 B | gemm 35328 B -> 41216 B (3 blocks/CU).
// tmp has a DEDICATED region (gemm0 writes m/aout concurrently — no aliasing).
__global__ void __launch_bounds__(512) fused0_kernel(
    const int* __restrict__ src, const int* __restrict__ dst,
    int* __restrict__ bcur, unsigned int* __restrict__ tmp,
    const float* __restrict__ x, const float* __restrict__ preW,
    const float* __restrict__ preb, const float* __restrict__ relW,
    const float* __restrict__ relb, const float* __restrict__ rootW,
    __half* __restrict__ m, __half* __restrict__ aout) {
    extern __shared__ __align__(16) char smem[];
    int tid = threadIdx.x;
    if (blockIdx.x < NCHUNK) {
        // ---------------- bucket branch (R1 bucket_kernel verbatim) ----------
        unsigned long long* ed = (unsigned long long*)smem;  // 32 KB
        int* cnt = (int*)(smem + 32768);
        int* cnt2 = (int*)(smem + 34368);
        int* scnx = (int*)(smem + 35968);
        int* gbase = (int*)(smem + 37568);
        int* s = (int*)(smem + 39168);                        // 2 KB -> 41216
        int bstart = blockIdx.x * TILE;
        int tcnt = N_EDGES - bstart;
        if (tcnt > TILE) tcnt = TILE;
        if (tcnt < 0) tcnt = 0;
        for (int b = tid; b < NBKT; b += 512) { cnt[b] = 0; cnt2[b] = 0; }
        __syncthreads();
        for (int i = tid; i < tcnt; i += 512) atomicAdd(&cnt[dst[bstart + i] >> BSH], 1);
        __syncthreads();
        s[tid] = (tid < NBKT) ? cnt[tid] : 0;
        __syncthreads();
        for (int off = 1; off < 512; off <<= 1) {
            int add = (tid >= off) ? s[tid - off] : 0;
            __syncthreads();
            s[tid] += add;
            __syncthreads();
        }
        if (tid < NBKT) {
            scnx[tid] = s[tid] - cnt[tid];
            gbase[tid] = tid * CAP + atomicAdd(&bcur[tid], cnt[tid]);
        }
        __syncthreads();
        for (int i = tid; i < tcnt; i += 512) {
            int e = bstart + i;
            int d = dst[e], sc = src[e];
            int b = d >> BSH;
            int pos = scnx[b] + atomicAdd(&cnt2[b], 1);
            ed[pos] = ((unsigned long long)(unsigned)d << 32) | (unsigned)sc;
        }
        __syncthreads();
        for (int i = tid; i < tcnt; i += 512) {
            unsigned long long v = ed[i];
            int d = (int)(v >> 32);
            unsigned sc = (unsigned)v;
            int b = d >> BSH;
            int idx = gbase[b] + (i - scnx[b]);
            if (idx < (b + 1) * CAP)  // statistically unreachable guard
                tmp[idx] = ((unsigned)(d & 255) << 17) | sc;
        }
    } else {
        // ---------------- PRE gemm branch: 512 thr, one 128-node tile --------
        __half* hs = (__half*)smem;              // 16 KB
        __half* ws = (__half*)(smem + 16384);    // 16 KB
        float* xs = (float*)(smem + 32768);      // 384 f
        float* pw = (float*)(smem + 34304);      // 192 f
        float* pbs = (float*)(smem + 35072);     // 64 f -> 35328
        int g = blockIdx.x - NCHUNK;
        int i0 = g * 128;
        // stage weights fp32->fp16 swizzled: 1024 16B chunks over 512 threads
#pragma unroll
        for (int it = 0; it < 2; it++) {
            int t = it * 512 + tid;
            int row = t >> 3, c = t & 7;
            const float* wsrc = (row < 64) ? &relW[row * 64 + c * 8]
                                           : &rootW[(row - 64) * 64 + c * 8];
            float4 w0 = *(const float4*)wsrc;
            float4 w1 = *(const float4*)(wsrc + 4);
            uint4 pk;
            __half2* hp = (__half2*)&pk;
            hp[0] = __floats2half2_rn(w0.x, w0.y);
            hp[1] = __floats2half2_rn(w0.z, w0.w);
            hp[2] = __floats2half2_rn(w1.x, w1.y);
            hp[3] = __floats2half2_rn(w1.z, w1.w);
            *(uint4*)&ws[row * 64 + ((c ^ (row & 7)) << 3)] = pk;
        }
        if (tid < 192) pw[tid] = preW[tid];
        if (tid < 64) pbs[tid] = preb[tid];
        if (tid < 384) {  // 512 threads fully cover xs[0..383] (R11-bug note)
            int gi = i0 * 3 + tid;
            xs[tid] = (gi < N_NODES * 3) ? x[gi] : 0.f;
        }
        __syncthreads();
#pragma unroll
        for (int it = 0; it < 2; it++) {
            int t = it * 512 + tid;
            int row = t >> 3, c = t & 7;
            float v[8];
#pragma unroll
            for (int u = 0; u < 8; u++) {
                int col = c * 8 + u;
                float sv = pbs[col];
                sv = fmaf(xs[row * 3 + 0], pw[col * 3 + 0], sv);
                sv = fmaf(xs[row * 3 + 1], pw[col * 3 + 1], sv);
                sv = fmaf(xs[row * 3 + 2], pw[col * 3 + 2], sv);
                v[u] = fmaxf(sv, 0.f);
            }
            uint4 pk;
            __half2* hp = (__half2*)&pk;
            hp[0] = __floats2half2_rn(v[0], v[1]);
            hp[1] = __floats2half2_rn(v[2], v[3]);
            hp[2] = __floats2half2_rn(v[4], v[5]);
            hp[3] = __floats2half2_rn(v[6], v[7]);
            *(uint4*)&hs[row * 64 + ((c ^ (row & 7)) << 3)] = pk;
        }
        __syncthreads();
        int lane = tid & 63;
        int w = tid >> 6;             // wave 0..7
        int wm = w >> 1, wn = w & 1;  // 4x2 wave grid: 32-row quarter x 64-col half
        int r = lane & 15, q = lane >> 4;
        f32x4 acc[2][4];
#pragma unroll
        for (int mt = 0; mt < 2; mt++)
#pragma unroll
            for (int nt = 0; nt < 4; nt++) acc[mt][nt] = (f32x4){0.f, 0.f, 0.f, 0.f};
#pragma unroll
        for (int ks = 0; ks < 2; ks++) {
            f16x8 af[2], bf[4];
#pragma unroll
            for (int mt = 0; mt < 2; mt++) {
                int row = wm * 32 + mt * 16 + r;
                int cc = (ks * 4 + q) ^ (row & 7);
                af[mt] = *(const f16x8*)&hs[row * 64 + (cc << 3)];
            }
#pragma unroll
            for (int nt = 0; nt < 4; nt++) {
                int row = wn * 64 + nt * 16 + r;
                int cc = (ks * 4 + q) ^ (row & 7);
                bf[nt] = *(const f16x8*)&ws[row * 64 + (cc << 3)];
            }
#pragma unroll
            for (int mt = 0; mt < 2; mt++)
#pragma unroll
                for (int nt = 0; nt < 4; nt++)
                    acc[mt][nt] = __builtin_amdgcn_mfma_f32_16x16x32_f16(af[mt], bf[nt],
                                                                         acc[mt][nt], 0, 0, 0);
        }
        if (wn == 0) {
#pragma unroll
            for (int mt = 0; mt < 2; mt++) {
                int nb = i0 + wm * 32 + mt * 16 + q * 4;
#pragma unroll
                for (int reg = 0; reg < 4; reg++) {
                    int node = nb + reg;
                    if (node >= N_NODES) continue;
#pragma unroll
                    for (int nt = 0; nt < 4; nt++)
                        m[(long)node * 64 + nt * 16 + r] = __float2half(acc[mt][nt][reg]);
                }
            }
        } else {
            float rb[4];
#pragma unroll
            for (int nt = 0; nt < 4; nt++) rb[nt] = relb[nt * 16 + r] * HSC;
#pragma unroll
            for (int mt = 0; mt < 2; mt++) {
                int nb = i0 + wm * 32 + mt * 16 + q * 4;
#pragma unroll
                for (int reg = 0; reg < 4; reg++) {
                    int node = nb + reg;
                    if (node >= N_NODES) continue;
#pragma unroll
                    for (int nt = 0; nt < 4; nt++)
                        aout[(long)node * 64 + nt * 16 + r] =
                            __float2half(fmaf(acc[mt][nt][reg], HSC, rb[nt]));
                }
            }
        }
    }
}

// Pass B: per bucket. Computes its own global offset lo = sum_{b'<b} cnt[b']
// (fused scan), then node degrees in LDS, scan -> rowp, counting-sort scatter.
__global__ void __launch_bounds__(256) passb_kernel(const unsigned int* __restrict__ tmp,
                                                    const int* __restrict__ bcur,
                                                    int* __restrict__ rowp,
                                                    int* __restrict__ ssrc) {
    __shared__ int red[256];
    __shared__ int cnt[256], s[256], cur[256];
    int tid = threadIdx.x;
    int b = blockIdx.x;
    int acc = 0;
    for (int i = tid; i < b; i += 256) {
        int c = bcur[i];
        if (c > CAP) c = CAP;
        acc += c;
    }
    red[tid] = acc;
    __syncthreads();
    for (int off = 128; off >= 1; off >>= 1) {
        if (tid < off) red[tid] += red[tid + off];
        __syncthreads();
    }
    int lo = red[0];
    int ne = bcur[b];
    if (ne > CAP) ne = CAP;
    if (b == NBKT - 1 && tid == 0) rowp[N_NODES] = lo + ne;
    int lo_t = b * CAP;
    cnt[tid] = 0;
    __syncthreads();
    for (int i = tid; i < ne; i += 256) atomicAdd(&cnt[tmp[lo_t + i] >> 17], 1);
    __syncthreads();
    int v = cnt[tid];
    s[tid] = v;
    __syncthreads();
    for (int off = 1; off < 256; off <<= 1) {
        int a = (tid >= off) ? s[tid - off] : 0;
        __syncthreads();
        s[tid] += a;
        __syncthreads();
    }
    int excl = lo + s[tid] - v;
    int node = (b << BSH) + tid;
    if (node < N_NODES) rowp[node] = excl;
    cur[tid] = excl;
    __syncthreads();
    for (int i = tid; i < ne; i += 256) {
        unsigned u = tmp[lo_t + i];
        int pos = atomicAdd(&cur[u >> 17], 1);
        ssrc[pos] = (int)(u & 0x1FFFF);
    }
}

// MFMA f16 dual GEMM (layers 1-2, PRE=0 path only): m = A @ relW.T,
// aout = A @ rootW.T + relb*HSC, A = HSC*h fp16. 256 thr, 4 waves 2x2,
// acc[4][4]. LDS fp16 16B-chunk XOR swizzle. All loads default-cached
// (R3 post-mortem: nontemporal hints regressed +16 µs — do not reintroduce).
__global__ void __launch_bounds__(256) gemmt_kernel(const __half* __restrict__ h,
                                                    const float* __restrict__ relW,
                                                    const float* __restrict__ relb,
                                                    const float* __restrict__ rootW,
                                                    __half* __restrict__ m,
                                                    __half* __restrict__ aout) {
    __shared__ __align__(16) __half hs[128 * 64];
    __shared__ __align__(16) __half ws[128 * 64];
    int tid = threadIdx.x;
    int i0 = blockIdx.x * 128;
#pragma unroll
    for (int it = 0; it < 4; it++) {
        int t = it * 256 + tid;
        int row = t >> 3, c = t & 7;
        const float* wsrc = (row < 64) ? &relW[row * 64 + c * 8]
                                       : &rootW[(row - 64) * 64 + c * 8];
        float4 w0 = *(const float4*)wsrc;
        float4 w1 = *(const float4*)(wsrc + 4);
        uint4 pk;
        __half2* hp = (__half2*)&pk;
        hp[0] = __floats2half2_rn(w0.x, w0.y);
        hp[1] = __floats2half2_rn(w0.z, w0.w);
        hp[2] = __floats2half2_rn(w1.x, w1.y);
        hp[3] = __floats2half2_rn(w1.z, w1.w);
        *(uint4*)&ws[row * 64 + ((c ^ (row & 7)) << 3)] = pk;
    }
#pragma unroll
    for (int it = 0; it < 4; it++) {
        int t = it * 256 + tid;
        int row = t >> 3, c = t & 7;
        uint4 hv = {0u, 0u, 0u, 0u};
        if (i0 + row < N_NODES) hv = *(const uint4*)(h + (long)(i0 + row) * 64 + c * 8);
        *(uint4*)&hs[row * 64 + ((c ^ (row & 7)) << 3)] = hv;
    }
    __syncthreads();

    int lane = tid & 63;
    int w = tid >> 6;
    int wm = w >> 1, wn = w & 1;
    int r = lane & 15, q = lane >> 4;
    f32x4 acc[4][4];
#pragma unroll
    for (int mt = 0; mt < 4; mt++)
#pragma unroll
        for (int nt = 0; nt < 4; nt++) acc[mt][nt] = (f32x4){0.f, 0.f, 0.f, 0.f};
#pragma unroll
    for (int ks = 0; ks < 2; ks++) {
        f16x8 af[4], bf[4];
#pragma unroll
        for (int mt = 0; mt < 4; mt++) {
            int row = wm * 64 + mt * 16 + r;
            int cc = (ks * 4 + q) ^ (row & 7);
            af[mt] = *(const f16x8*)&hs[row * 64 + (cc << 3)];
        }
#pragma unroll
        for (int nt = 0; nt < 4; nt++) {
            int row = wn * 64 + nt * 16 + r;
            int cc = (ks * 4 + q) ^ (row & 7);
            bf[nt] = *(const f16x8*)&ws[row * 64 + (cc << 3)];
        }
#pragma unroll
        for (int mt = 0; mt < 4; mt++)
#pragma unroll
            for (int nt = 0; nt < 4; nt++)
                acc[mt][nt] = __builtin_amdgcn_mfma_f32_16x16x32_f16(af[mt], bf[nt],
                                                                     acc[mt][nt], 0, 0, 0);
    }
    if (wn == 0) {
#pragma unroll
        for (int mt = 0; mt < 4; mt++) {
            int nb = i0 + wm * 64 + mt * 16 + q * 4;
#pragma unroll
            for (int reg = 0; reg < 4; reg++) {
                int node = nb + reg;
                if (node >= N_NODES) continue;
#pragma unroll
                for (int nt = 0; nt < 4; nt++)
                    m[(long)node * 64 + nt * 16 + r] = __float2half(acc[mt][nt][reg]);
            }
        }
    } else {
        float rb[4];
#pragma unroll
        for (int nt = 0; nt < 4; nt++) rb[nt] = relb[nt * 16 + r] * HSC;
#pragma unroll
        for (int mt = 0; mt < 4; mt++) {
            int nb = i0 + wm * 64 + mt * 16 + q * 4;
#pragma unroll
            for (int reg = 0; reg < 4; reg++) {
                int node = nb + reg;
                if (node >= N_NODES) continue;
#pragma unroll
                for (int nt = 0; nt < 4; nt++)
                    aout[(long)node * 64 + nt * 16 + r] =
                        __float2half(fmaf(acc[mt][nt][reg], 1.0f, rb[nt]));
            }
        }
    }
}

// fp16-m gather (R1-verbatim, best measured): 4 nodes per wave, 2 edge
// subgroups, 4-pair unroll, fp32 accumulate, hoisted root term.
template <int FINAL>
__global__ void gather_kernel(const __half* __restrict__ m, __half* __restrict__ a,
                              const int* __restrict__ rowp, const int* __restrict__ ssrc,
                              float aggscale,
                              const float* __restrict__ postW, const float* __restrict__ postb,
                              float* __restrict__ out) {
    int lane = threadIdx.x & 63;
    int wv = (blockIdx.x * blockDim.x + threadIdx.x) >> 6;
    int pb = wv * 4;
    if (pb >= N_NODES) return;
    int n = lane >> 4;          // node quarter 0..3
    int g = (lane >> 3) & 1;    // edge subgroup 0/1
    int f8 = (lane & 7) << 3;   // feature base 0,8,...,56
    pb = __builtin_amdgcn_readfirstlane(pb);
    int q0 = rowp[pb], q1 = rowp[pb + 1], q2 = rowp[pb + 2];
    int q3 = rowp[pb + 3], q4 = rowp[pb + 4];
    int node = pb + n;
    int r0 = (n == 0) ? q0 : (n == 1) ? q1 : (n == 2) ? q2 : q3;
    int r1 = (n == 0) ? q1 : (n == 1) ? q2 : (n == 2) ? q3 : q4;
    int nedge = r1 - r0;
    uint4 av = *(const uint4*)(a + (long)node * 64 + f8);
    float a0 = 0.f, a1 = 0.f, a2 = 0.f, a3 = 0.f, a4 = 0.f, a5 = 0.f, a6 = 0.f, a7 = 0.f;
#define ACC8(u)                                                         \
    {                                                                   \
        float2 f_;                                                      \
        f_ = __half22float2(*(__half2*)&(u).x); a0 += f_.x; a1 += f_.y; \
        f_ = __half22float2(*(__half2*)&(u).y); a2 += f_.x; a3 += f_.y; \
        f_ = __half22float2(*(__half2*)&(u).z); a4 += f_.x; a5 += f_.y; \
        f_ = __half22float2(*(__half2*)&(u).w); a6 += f_.x; a7 += f_.y; \
    }
    int ns = nedge >> 1;
    int q = 0;
    for (; q + 4 <= ns; q += 4) {
        int b0 = r0 + q * 2 + g;
        int i0 = ssrc[b0];
        int i1 = ssrc[b0 + 2];
        int i2 = ssrc[b0 + 4];
        int i3 = ssrc[b0 + 6];
        uint4 u0 = *(const uint4*)(m + (long)i0 * 64 + f8);
        uint4 u1 = *(const uint4*)(m + (long)i1 * 64 + f8);
        uint4 u2 = *(const uint4*)(m + (long)i2 * 64 + f8);
        uint4 u3 = *(const uint4*)(m + (long)i3 * 64 + f8);
        ACC8(u0); ACC8(u1); ACC8(u2); ACC8(u3);
    }
    if (q + 2 <= ns) {
        int b0 = r0 + q * 2 + g;
        int i0 = ssrc[b0];
        int i1 = ssrc[b0 + 2];
        uint4 u0 = *(const uint4*)(m + (long)i0 * 64 + f8);
        uint4 u1 = *(const uint4*)(m + (long)i1 * 64 + f8);
        ACC8(u0); ACC8(u1);
        q += 2;
    }
    if (q < ns) {
        int i0 = ssrc[r0 + q * 2 + g];
        uint4 u0 = *(const uint4*)(m + (long)i0 * 64 + f8);
        ACC8(u0);
    }
    if ((nedge & 1) && g == 0) {
        int i0 = ssrc[r0 + ns * 2];
        uint4 u0 = *(const uint4*)(m + (long)i0 * 64 + f8);
        ACC8(u0);
    }
#undef ACC8
    a0 += __shfl_xor(a0, 8, 64); a1 += __shfl_xor(a1, 8, 64);
    a2 += __shfl_xor(a2, 8, 64); a3 += __shfl_xor(a3, 8, 64);
    a4 += __shfl_xor(a4, 8, 64); a5 += __shfl_xor(a5, 8, 64);
    a6 += __shfl_xor(a6, 8, 64); a7 += __shfl_xor(a7, 8, 64);
    a0 *= aggscale; a1 *= aggscale; a2 *= aggscale; a3 *= aggscale;
    a4 *= aggscale; a5 *= aggscale; a6 *= aggscale; a7 *= aggscale;
    const __half2* ap = (const __half2*)&av;
    float2 o0 = __half22float2(ap[0]), o1 = __half22float2(ap[1]);
    float2 o2 = __half22float2(ap[2]), o3 = __half22float2(ap[3]);
    a0 = fmaxf(fmaf(o0.x, HSCI, a0), 0.f); a1 = fmaxf(fmaf(o0.y, HSCI, a1), 0.f);
    a2 = fmaxf(fmaf(o1.x, HSCI, a2), 0.f); a3 = fmaxf(fmaf(o1.y, HSCI, a3), 0.f);
    a4 = fmaxf(fmaf(o2.x, HSCI, a4), 0.f); a5 = fmaxf(fmaf(o2.y, HSCI, a5), 0.f);
    a6 = fmaxf(fmaf(o3.x, HSCI, a6), 0.f); a7 = fmaxf(fmaf(o3.y, HSCI, a7), 0.f);
    if (FINAL) {
        float4 w0 = *(const float4*)(postW + f8);
        float4 w1 = *(const float4*)(postW + f8 + 4);
        float4 w2 = *(const float4*)(postW + 64 + f8);
        float4 w3 = *(const float4*)(postW + 64 + f8 + 4);
        float p0 = a0 * w0.x + a1 * w0.y + a2 * w0.z + a3 * w0.w +
                   a4 * w1.x + a5 * w1.y + a6 * w1.z + a7 * w1.w;
        float p1 = a0 * w2.x + a1 * w2.y + a2 * w2.z + a3 * w2.w +
                   a4 * w3.x + a5 * w3.y + a6 * w3.z + a7 * w3.w;
#pragma unroll
        for (int off = 1; off <= 4; off <<= 1) {
            p0 += __shfl_xor(p0, off, 64);
            p1 += __shfl_xor(p1, off, 64);
        }
        if ((lane & 15) == 0) {
            out[(long)node * 2 + 0] = fmaxf(p0 + postb[0], 0.f);
            out[(long)node * 2 + 1] = fmaxf(p1 + postb[1], 0.f);
        }
    } else {
        if (g == 0) {
            uint4 st;
            __half2* sp = (__half2*)&st;
            sp[0] = __floats2half2_rn(a0 * HSC, a1 * HSC);
            sp[1] = __floats2half2_rn(a2 * HSC, a3 * HSC);
            sp[2] = __floats2half2_rn(a4 * HSC, a5 * HSC);
            sp[3] = __floats2half2_rn(a6 * HSC, a7 * HSC);
            *(uint4*)(a + (long)node * 64 + f8) = st;
        }
    }
}

extern "C" void kernel_launch(void* const* d_in, const int* in_sizes, int n_in,
                              void* d_out, int out_size, void* d_ws, size_t ws_size,
                              hipStream_t stream) {
    const float* x = (const float*)d_in[0];
    const int* esrc = (const int*)d_in[1];
    const int* edst = esrc + N_EDGES;
    const float* preW = (const float*)d_in[2];
    const float* preb = (const float*)d_in[3];
    const float* postW = (const float*)d_in[4];
    const float* postb = (const float*)d_in[5];
    const float* relW[3] = {(const float*)d_in[6], (const float*)d_in[9], (const float*)d_in[12]};
    const float* relb[3] = {(const float*)d_in[7], (const float*)d_in[10], (const float*)d_in[13]};
    const float* rootW[3] = {(const float*)d_in[8], (const float*)d_in[11], (const float*)d_in[14]};
    float* out = (float*)d_out;

    const size_t NF = (size_t)N_NODES * HID;
    char* p = (char*)d_ws;
    __half* hA = (__half*)p; p += NF * 2;
    __half* hB = (__half*)p; p += NF * 2;
    __half* mB = (__half*)p; p += NF * 2;
    p = (char*)(((size_t)p + 255) & ~(size_t)255);
    int* rowp = (int*)p; p += (size_t)(N_NODES + 1) * 4;
    p = (char*)(((size_t)p + 255) & ~(size_t)255);
    int* ssrc = (int*)p; p += (size_t)N_EDGES * 4;
    p = (char*)(((size_t)p + 255) & ~(size_t)255);
    // tmp DEDICATED (9.6 MB): gemm0 runs concurrently with bucketing in the
    // fused kernel, so tmp must NOT alias hA/hB/mB.
    unsigned int* tmp = (unsigned int*)p; p += (size_t)NBKT * CAP * 4;
    int* bcur = (int*)p; p += 512 * 4;

    const int GEMM_BLOCKS = (N_NODES + 127) / 128;      // 782
    const int GATHER_BLOCKS = N_NODES / 16;             // 4 nodes/wave, 4 waves/block
    const float IS1 = 64.0f;  // layers 1-2 m fp16 range scaling inverse

    hipMemsetAsync(bcur, 0, 512 * 4, stream);
    // fused: {bucket 391 blocks} ∥ {layer-0 PRE gemm 782 blocks}; dyn LDS 41216 B
    fused0_kernel<<<NCHUNK + GEMM_BLOCKS, 512, 41216, stream>>>(
        esrc, edst, bcur, tmp, x, preW, preb, relW[0], relb[0], rootW[0], mB, hB);
    passb_kernel<<<NBKT, 256, 0, stream>>>(tmp, bcur, rowp, ssrc);

    gather_kernel<0><<<GATHER_BLOCKS, 256, 0, stream>>>(mB, hB, rowp, ssrc, 1.0f,
                                                        nullptr, nullptr, nullptr);
    // layer 1: hB -> mB, hA(aout)
    gemmt_kernel<<<GEMM_BLOCKS, 256, 0, stream>>>(hB, relW[1], relb[1], rootW[1], mB, hA);
    gather_kernel<0><<<GATHER_BLOCKS, 256, 0, stream>>>(mB, hA, rowp, ssrc, IS1,
                                                        nullptr, nullptr, nullptr);
    // layer 2 + post: hA -> out
    gemmt_kernel<<<GEMM_BLOCKS, 256, 0, stream>>>(hA, relW[2], relb[2], rootW[2], mB, hB);
    gather_kernel<1><<<GATHER_BLOCKS, 256, 0, stream>>>(mB, hB, rowp, ssrc, IS1,
                                                        postW, postb, out);
}